// Round 4
// baseline (118.031 us; speedup 1.0000x reference)
//
#include <hip/hip_runtime.h>
#include <hip/hip_cooperative_groups.h>

namespace cg = cooperative_groups;

// VectorQuantizer (per-dim scalar codebooks), B=2048, D=128, K=512.
// out[0] = mean (q-z)^2 ; out[1..] = z + (q - z)  [B,D] row-major.
//
// R4: single cooperative kernel (1 graph node instead of 2).
//   Phase 1 = R3's scan, byte-identical: 2.5 VALU ops/code keyed argmin
//   (key = rotl1(bits(c-z)) orders by |diff| == order of (z-c)^2).
//   grid.sync(), then block 0 reduces the 1024 per-block partials.
//   All fp summation orders identical to the passing R3.

#define B_N 2048
#define D_N 128
#define K_N 512
#define NBLK ((B_N / 256) * D_N)  // 1024

__device__ __forceinline__ unsigned rotl1(unsigned x) { return (x << 1) | (x >> 31); }
__device__ __forceinline__ unsigned umin3(unsigned a, unsigned b, unsigned c) {
    return min(min(a, b), c);  // -> v_min3_u32
}

__global__ __launch_bounds__(256) void vq_fused_kernel(
    const float* __restrict__ z,
    const float* __restrict__ cbk,
    float* __restrict__ out,
    float* __restrict__ partial) {
    const int d = blockIdx.x & (D_N - 1);
    const int btile = blockIdx.x >> 7;
    const int b = (btile << 8) + threadIdx.x;

    const float zv = z[b * D_N + d];
    const float* __restrict__ crow = cbk + d * K_N;  // wave-uniform -> s_load

    unsigned bestA = 0xFFFFFFFFu, bestB = 0xFFFFFFFFu;

    #pragma unroll
    for (int k0 = 0; k0 < K_N; k0 += 4) {
        float c0 = crow[k0 + 0], c1 = crow[k0 + 1];
        float c2 = crow[k0 + 2], c3 = crow[k0 + 3];
        unsigned q0 = rotl1(__float_as_uint(c0 - zv));
        unsigned q1 = rotl1(__float_as_uint(c1 - zv));
        unsigned q2 = rotl1(__float_as_uint(c2 - zv));
        unsigned q3 = rotl1(__float_as_uint(c3 - zv));
        bestA = umin3(q0, q1, bestA);
        bestB = umin3(q2, q3, bestB);
    }

    unsigned best = min(bestA, bestB);
    float diff = __uint_as_float((best >> 1) | (best << 31));  // fl(q - z)

    out[1 + b * D_N + d] = zv + diff;  // same fp order as reference ST output

    // per-block loss partial (identical structure/order to R3)
    float p = diff * diff;
    #pragma unroll
    for (int off = 32; off > 0; off >>= 1) p += __shfl_down(p, off, 64);

    __shared__ float wsum[4];
    const int lane = threadIdx.x & 63;
    const int wid = threadIdx.x >> 6;
    if (lane == 0) wsum[wid] = p;
    __syncthreads();
    if (threadIdx.x == 0)
        partial[blockIdx.x] = (wsum[0] + wsum[1]) + (wsum[2] + wsum[3]);

    cg::this_grid().sync();  // device-wide barrier + memory visibility

    if (blockIdx.x == 0) {
        float q = 0.0f;
        #pragma unroll
        for (int j = 0; j < 4; ++j) q += partial[threadIdx.x + 256 * j];
        #pragma unroll
        for (int off = 32; off > 0; off >>= 1) q += __shfl_down(q, off, 64);
        if (lane == 0) wsum[wid] = q;
        __syncthreads();
        if (threadIdx.x == 0) {
            float s = (wsum[0] + wsum[1]) + (wsum[2] + wsum[3]);
            out[0] = s * (1.0f / (B_N * D_N));
        }
    }
}

extern "C" void kernel_launch(void* const* d_in, const int* in_sizes, int n_in,
                              void* d_out, int out_size, void* d_ws, size_t ws_size,
                              hipStream_t stream) {
    const float* z  = (const float*)d_in[0];
    const float* cb = (const float*)d_in[1];
    float* out = (float*)d_out;
    float* partial = (float*)d_ws;  // NBLK floats, fully overwritten each call

    void* args[] = {(void*)&z, (void*)&cb, (void*)&out, (void*)&partial};
    hipLaunchCooperativeKernel((const void*)vq_fused_kernel,
                               dim3(NBLK), dim3(256), args, 0, stream);
}

// Round 5
// 18.979 us; speedup vs baseline: 6.2192x; 6.2192x over previous
//
#include <hip/hip_runtime.h>

// VectorQuantizer (per-dim scalar codebooks), B=2048, D=128, K=512.
// out[0] = mean (q-z)^2 ; out[1..] = z + (q - z)  [B,D] row-major.
//
// R5: sort-then-search. One fused kernel, 256 blocks x 1024 threads,
// block = (d, half-batch of 1024):
//  A) 512 threads build distinct order-keys: (orderable_u32(c) & ~511) | idx
//     -> written to ws so phase B can scan them as wave-uniform s_loads.
//  B) rank-sort: rank[e] = #{keys < key_e} (2 VALU/key), distinct keys ->
//     ranks are a permutation.
//  C) scatter sorted values into LDS.
//  D) all 1024 threads: branchless 10-probe upper_bound in LDS, then the
//     R3 rotl1-key compare on the two bracketing codes (identical tie-break:
//     orders by |diff|, positive diff wins exact ties).
// Reduce kernel (node 2) sums 256 per-block partials into out[0].

#define B_N 2048
#define D_N 128
#define K_N 512
#define NBLK 256  // 2 blocks per d

__device__ __forceinline__ unsigned rotl1(unsigned x) { return (x << 1) | (x >> 31); }

__global__ __launch_bounds__(1024) void vq_main_kernel(
    const float* __restrict__ z,
    const float* __restrict__ cbk,
    float* __restrict__ out,
    unsigned* __restrict__ wkeys,    // [D_N][K_N] u32 keys
    float* __restrict__ partial) {   // [NBLK]
    __shared__ float ss[K_N];        // sorted codebook row
    __shared__ float wsum[16];

    const int d = blockIdx.x >> 1;
    const int half = blockIdx.x & 1;
    const int t = threadIdx.x;

    unsigned* __restrict__ krow = wkeys + d * K_N;

    // A: build distinct order-preserving keys, stash to global for s_load scan
    float cval = 0.0f;
    unsigned mykey = 0u;
    if (t < K_N) {
        cval = cbk[d * K_N + t];
        unsigned u = __float_as_uint(cval);
        unsigned m = (unsigned)(((int)u) >> 31) | 0x80000000u;
        mykey = ((u ^ m) & ~(unsigned)(K_N - 1)) | (unsigned)t;
        krow[t] = mykey;
    }
    __syncthreads();  // drains vmcnt(0): stores in L2 before the key scan

    // B+C: rank each element (keys distinct -> permutation), scatter to LDS
    if (t < K_N) {
        int rank = 0;
        #pragma unroll
        for (int k = 0; k < K_N; ++k)
            rank += (krow[k] < mykey) ? 1 : 0;   // uniform addr -> s_load
        ss[rank] = cval;
    }
    __syncthreads();

    // D: per-element branchless upper_bound + 2-candidate keyed min
    const int b = (half << 10) + t;
    const float zv = z[b * D_N + d];

    int pos = 0;
    #pragma unroll
    for (int step = 256; step > 0; step >>= 1)
        pos += (ss[pos + step - 1] <= zv) ? step : 0;   // probes <= 510
    pos += (ss[pos] <= zv) ? 1 : 0;                     // pos in [0,512]

    const int iLo = max(pos - 1, 0);
    const int iHi = min(pos, K_N - 1);
    const float dLo = ss[iLo] - zv;
    const float dHi = ss[iHi] - zv;
    const unsigned kLo = rotl1(__float_as_uint(dLo));
    const unsigned kHi = rotl1(__float_as_uint(dHi));
    const unsigned best = min(kLo, kHi);
    const float diff = __uint_as_float((best >> 1) | (best << 31));  // fl(q-z)

    out[1 + b * D_N + d] = zv + diff;  // same fp order as reference

    // block partial of (q-z)^2
    float p = diff * diff;
    #pragma unroll
    for (int off = 32; off > 0; off >>= 1) p += __shfl_down(p, off, 64);
    const int lane = t & 63;
    const int wid = t >> 6;
    if (lane == 0) wsum[wid] = p;
    __syncthreads();
    if (t == 0) {
        float s = 0.0f;
        #pragma unroll
        for (int w = 0; w < 16; ++w) s += wsum[w];
        partial[blockIdx.x] = s;
    }
}

__global__ __launch_bounds__(256) void vq_reduce_kernel(
    const float* __restrict__ partial, float* __restrict__ out) {
    float p = partial[threadIdx.x];  // NBLK == 256
    #pragma unroll
    for (int off = 32; off > 0; off >>= 1) p += __shfl_down(p, off, 64);
    __shared__ float wsum[4];
    const int lane = threadIdx.x & 63;
    const int wid = threadIdx.x >> 6;
    if (lane == 0) wsum[wid] = p;
    __syncthreads();
    if (threadIdx.x == 0) {
        float s = (wsum[0] + wsum[1]) + (wsum[2] + wsum[3]);
        out[0] = s * (1.0f / (B_N * D_N));
    }
}

extern "C" void kernel_launch(void* const* d_in, const int* in_sizes, int n_in,
                              void* d_out, int out_size, void* d_ws, size_t ws_size,
                              hipStream_t stream) {
    const float* z  = (const float*)d_in[0];
    const float* cb = (const float*)d_in[1];
    float* out = (float*)d_out;
    unsigned* wkeys = (unsigned*)d_ws;                  // 256 KB
    float* partial = (float*)d_ws + D_N * K_N;          // next NBLK floats

    vq_main_kernel<<<NBLK, 1024, 0, stream>>>(z, cb, out, wkeys, partial);
    vq_reduce_kernel<<<1, 256, 0, stream>>>(partial, out);
}

// Round 6
// 16.986 us; speedup vs baseline: 6.9485x; 1.1173x over previous
//
#include <hip/hip_runtime.h>

// VectorQuantizer (per-dim scalar codebooks), B=2048, D=128, K=512.
// out[0] = mean (q-z)^2 ; out[1..] = z + (q - z)  [B,D] row-major.
//
// R6: 1.5-VALU-op/code exact scan.
//  per 2 codes: v_pk_add_f32 (SGPR-pair c + {-z,-z})  -> d0,d1 = fl(c-z)
//               v_min3_f32(|d0|,|d1|,accF)            -> m = min |diff| (exact)
//               v_min3_u32(bits d0, bits d1, accU)    -> smallest POSITIVE diff
//  diff = (accU == bits(m)) ? +m : -m   (positive wins ties, same rule as the
//  bit-exact R3 kernel; loss = m*m is sign-independent).
// Reduce kernel identical to R3.

#define B_N 2048
#define D_N 128
#define K_N 512
#define NBLK ((B_N / 256) * D_N)  // 1024

typedef float v2f __attribute__((ext_vector_type(2)));

__global__ __launch_bounds__(256) void vq_scan_kernel(
    const float* __restrict__ z,
    const float* __restrict__ cbk,
    float* __restrict__ out,
    float* __restrict__ partial) {
    const int d = blockIdx.x & (D_N - 1);
    const int btile = blockIdx.x >> 7;
    const int b = (btile << 8) + threadIdx.x;

    const float zv = z[b * D_N + d];
    // wave-uniform codebook row, read as double pairs -> s_load into SGPR pairs
    const double* __restrict__ crowd = (const double*)(cbk + d * K_N);

    v2f mz;
    mz.x = -zv;
    mz.y = -zv;

    float accF0 = 3.402823466e+38f, accF1 = 3.402823466e+38f;
    float accF2 = 3.402823466e+38f, accF3 = 3.402823466e+38f;
    unsigned accU0 = 0xFFFFFFFFu, accU1 = 0xFFFFFFFFu;
    unsigned accU2 = 0xFFFFFFFFu, accU3 = 0xFFFFFFFFu;

    #pragma unroll
    for (int j = 0; j < K_N / 8; ++j) {  // 8 codes (4 pairs) per iteration
        double cd0 = crowd[4 * j + 0];
        double cd1 = crowd[4 * j + 1];
        double cd2 = crowd[4 * j + 2];
        double cd3 = crowd[4 * j + 3];
        v2f d0, d1, d2, d3;
        asm("v_pk_add_f32 %0, %1, %2" : "=v"(d0) : "s"(cd0), "v"(mz));
        asm("v_pk_add_f32 %0, %1, %2" : "=v"(d1) : "s"(cd1), "v"(mz));
        asm("v_pk_add_f32 %0, %1, %2" : "=v"(d2) : "s"(cd2), "v"(mz));
        asm("v_pk_add_f32 %0, %1, %2" : "=v"(d3) : "s"(cd3), "v"(mz));
        accF0 = fminf(fminf(fabsf(d0.x), fabsf(d0.y)), accF0);   // v_min3_f32 |a|,|b|,acc
        accU0 = min(min(__float_as_uint(d0.x), __float_as_uint(d0.y)), accU0);  // v_min3_u32
        accF1 = fminf(fminf(fabsf(d1.x), fabsf(d1.y)), accF1);
        accU1 = min(min(__float_as_uint(d1.x), __float_as_uint(d1.y)), accU1);
        accF2 = fminf(fminf(fabsf(d2.x), fabsf(d2.y)), accF2);
        accU2 = min(min(__float_as_uint(d2.x), __float_as_uint(d2.y)), accU2);
        accF3 = fminf(fminf(fabsf(d3.x), fabsf(d3.y)), accF3);
        accU3 = min(min(__float_as_uint(d3.x), __float_as_uint(d3.y)), accU3);
    }

    const float m = fminf(fminf(accF0, accF1), fminf(accF2, accF3));
    const unsigned mu = min(min(accU0, accU1), min(accU2, accU3));
    const unsigned mb = __float_as_uint(m);
    // +m chosen iff some code has diff exactly +m (smallest positive == m)
    const unsigned diffb = (mu == mb) ? mb : (mb | 0x80000000u);
    const float diff = __uint_as_float(diffb);  // fl(q - z), bit-identical to R3

    out[1 + b * D_N + d] = zv + diff;  // same fp order as reference ST output

    // loss partial: (q - z)^2 == m*m  (identical value/order to R3)
    float p = diff * diff;
    #pragma unroll
    for (int off = 32; off > 0; off >>= 1) p += __shfl_down(p, off, 64);

    __shared__ float wsum[4];
    const int lane = threadIdx.x & 63;
    const int wid = threadIdx.x >> 6;
    if (lane == 0) wsum[wid] = p;
    __syncthreads();
    if (threadIdx.x == 0)
        partial[blockIdx.x] = (wsum[0] + wsum[1]) + (wsum[2] + wsum[3]);
}

__global__ __launch_bounds__(256) void vq_reduce_kernel(
    const float* __restrict__ partial, float* __restrict__ out) {
    float p = 0.0f;
    #pragma unroll
    for (int j = 0; j < 4; ++j) p += partial[threadIdx.x + 256 * j];
    #pragma unroll
    for (int off = 32; off > 0; off >>= 1) p += __shfl_down(p, off, 64);

    __shared__ float wsum[4];
    const int lane = threadIdx.x & 63;
    const int wid = threadIdx.x >> 6;
    if (lane == 0) wsum[wid] = p;
    __syncthreads();
    if (threadIdx.x == 0) {
        float s = (wsum[0] + wsum[1]) + (wsum[2] + wsum[3]);
        out[0] = s * (1.0f / (B_N * D_N));
    }
}

extern "C" void kernel_launch(void* const* d_in, const int* in_sizes, int n_in,
                              void* d_out, int out_size, void* d_ws, size_t ws_size,
                              hipStream_t stream) {
    const float* z  = (const float*)d_in[0];
    const float* cb = (const float*)d_in[1];
    float* out = (float*)d_out;
    float* partial = (float*)d_ws;  // NBLK floats, fully overwritten each call

    vq_scan_kernel<<<NBLK, 256, 0, stream>>>(z, cb, out, partial);
    vq_reduce_kernel<<<1, 256, 0, stream>>>(partial, out);
}